// Round 1
// baseline (498.382 us; speedup 1.0000x reference)
//
#include <hip/hip_runtime.h>

// Problem constants (fixed by reference)
constexpr int NROWS = 2048;
constexpr int NCOLS = 32000;
constexpr int NC4   = NCOLS / 4;   // 8000 float4 per row
constexpr int NGRID = 100;
constexpr int NMID  = 99;
constexpr int BLOCK = 1024;        // 16 waves; 1 block/CU (LDS-limited) -> 16 waves/CU
constexpr int NWAVE = BLOCK / 64;

__device__ inline float waveMax(float v) {
    #pragma unroll
    for (int off = 32; off > 0; off >>= 1)
        v = fmaxf(v, __shfl_down(v, off, 64));
    return v;
}
__device__ inline float waveSum(float v) {
    #pragma unroll
    for (int off = 32; off > 0; off >>= 1)
        v += __shfl_down(v, off, 64);
    return v;
}

__global__ __launch_bounds__(BLOCK) void calib_kernel(
    const float* __restrict__ logits,
    const float* __restrict__ log_temperature,
    const float* __restrict__ iso_x,
    const float* __restrict__ iso_y,
    float* __restrict__ out)
{
    // 128 KB row buffer + small tables. gfx950: 160 KiB LDS/CU.
    __shared__ float zbuf[NCOLS];
    __shared__ float s_mids[NMID];
    __shared__ float s_y[NGRID];
    __shared__ float s_red[NWAVE];
    __shared__ float s_bcast;

    const int tid  = threadIdx.x;
    const int lane = tid & 63;
    const int wave = tid >> 6;
    const int row  = blockIdx.x;

    // temperature = clamp(exp(log_T), 0.1, 10.0) -- same fp32 ops as reference
    float T = expf(log_temperature[0]);
    T = fminf(fmaxf(T, 0.1f), 10.0f);

    // mids exactly as reference: 0.5*(x[i] + x[i+1]) in fp32
    if (tid < NMID)  s_mids[tid] = 0.5f * (iso_x[tid] + iso_x[tid + 1]);
    if (tid < NGRID) s_y[tid]    = iso_y[tid];

    const float4* __restrict__ row4 = reinterpret_cast<const float4*>(logits) + (size_t)row * NC4;
    float4* zb4 = reinterpret_cast<float4*>(zbuf);
    float4* out4 = reinterpret_cast<float4*>(out) + (size_t)row * NC4;

    // ---- Pass 1: global -> LDS, z = l / T (IEEE div, matches ref), track max
    float lmax = -__builtin_inff();
    for (int i = tid; i < NC4; i += BLOCK) {
        float4 v = row4[i];
        float4 z;
        z.x = v.x / T; z.y = v.y / T; z.z = v.z / T; z.w = v.w / T;
        zb4[i] = z;
        lmax = fmaxf(lmax, fmaxf(fmaxf(z.x, z.y), fmaxf(z.z, z.w)));
    }
    // block-reduce max
    lmax = waveMax(lmax);
    if (lane == 0) s_red[wave] = lmax;
    __syncthreads();
    if (tid == 0) {
        float m = s_red[0];
        #pragma unroll
        for (int w = 1; w < NWAVE; ++w) m = fmaxf(m, s_red[w]);
        s_bcast = m;
    }
    __syncthreads();
    const float m = s_bcast;

    // ---- Pass 2: sum of exp(z - m) from LDS
    float lsum = 0.0f;
    for (int i = tid; i < NC4; i += BLOCK) {
        float4 z = zb4[i];
        lsum += expf(z.x - m) + expf(z.y - m) + expf(z.z - m) + expf(z.w - m);
    }
    lsum = waveSum(lsum);
    if (lane == 0) s_red[wave] = lsum;
    __syncthreads();
    if (tid == 0) {
        float s = 0.0f;
        #pragma unroll
        for (int w = 0; w < NWAVE; ++w) s += s_red[w];
        s_bcast = s;
    }
    __syncthreads();
    const float S = s_bcast;

    // ---- Pass 3: p = exp(z - m) / S, idx = first i with mids[i] >= p, out = y[idx]
    for (int i = tid; i < NC4; i += BLOCK) {
        float4 z = zb4[i];
        float p0 = expf(z.x - m) / S;
        float p1 = expf(z.y - m) / S;
        float p2 = expf(z.z - m) / S;
        float p3 = expf(z.w - m) / S;
        float4 o;
        // linear scan: p <= mids[0] for ~all elements (probs ~ 1/32000)
        int i0 = 0; while (i0 < NMID && s_mids[i0] < p0) ++i0;
        int i1 = 0; while (i1 < NMID && s_mids[i1] < p1) ++i1;
        int i2 = 0; while (i2 < NMID && s_mids[i2] < p2) ++i2;
        int i3 = 0; while (i3 < NMID && s_mids[i3] < p3) ++i3;
        o.x = s_y[i0]; o.y = s_y[i1]; o.z = s_y[i2]; o.w = s_y[i3];
        out4[i] = o;
    }
}

extern "C" void kernel_launch(void* const* d_in, const int* in_sizes, int n_in,
                              void* d_out, int out_size, void* d_ws, size_t ws_size,
                              hipStream_t stream) {
    const float* logits = (const float*)d_in[0];
    const float* logT   = (const float*)d_in[1];
    const float* iso_x  = (const float*)d_in[2];
    const float* iso_y  = (const float*)d_in[3];
    float* out = (float*)d_out;
    calib_kernel<<<NROWS, BLOCK, 0, stream>>>(logits, logT, iso_x, iso_y, out);
}

// Round 3
// 457.187 us; speedup vs baseline: 1.0901x; 1.0901x over previous
//
#include <hip/hip_runtime.h>

// Problem constants (fixed by reference)
constexpr int NROWS = 2048;
constexpr int NCOLS = 32000;
constexpr int NC4   = NCOLS / 4;   // 8000 float4 per row
constexpr int NGRID = 100;
constexpr int NMID  = 99;
constexpr int BLOCK = 1024;        // 16 waves; 1 block/CU (LDS-limited)
constexpr int NWAVE = BLOCK / 64;

// clang-native vector type: accepted by __builtin_nontemporal_store
typedef float vfloat4 __attribute__((ext_vector_type(4)));

__device__ inline float waveMax(float v) {
    #pragma unroll
    for (int off = 32; off > 0; off >>= 1)
        v = fmaxf(v, __shfl_down(v, off, 64));
    return v;
}
__device__ inline float waveSum(float v) {
    #pragma unroll
    for (int off = 32; off > 0; off >>= 1)
        v += __shfl_down(v, off, 64);
    return v;
}

__global__ __launch_bounds__(BLOCK) void calib_kernel(
    const float* __restrict__ logits,
    const float* __restrict__ log_temperature,
    const float* __restrict__ iso_x,
    const float* __restrict__ iso_y,
    float* __restrict__ out)
{
    // 128 KB row buffer (l, then overwritten by e) + small tables.
    __shared__ float zbuf[NCOLS];
    __shared__ float s_mids[NMID];
    __shared__ float s_y[NGRID];
    __shared__ float s_red[NWAVE];
    __shared__ float s_bcast;

    const int tid  = threadIdx.x;
    const int lane = tid & 63;
    const int wave = tid >> 6;
    const int row  = blockIdx.x;

    // temperature = clamp(exp(log_T), 0.1, 10.0) -- same fp32 ops as reference
    float T = expf(log_temperature[0]);
    T = fminf(fmaxf(T, 0.1f), 10.0f);

    // mids exactly as reference: 0.5*(x[i] + x[i+1]) in fp32
    if (tid < NMID)  s_mids[tid] = 0.5f * (iso_x[tid] + iso_x[tid + 1]);
    if (tid < NGRID) s_y[tid]    = iso_y[tid];

    const float4* __restrict__ row4 = reinterpret_cast<const float4*>(logits) + (size_t)row * NC4;
    float4* zb4 = reinterpret_cast<float4*>(zbuf);
    vfloat4* out4 = reinterpret_cast<vfloat4*>(out) + (size_t)row * NC4;

    // ---- Pass 1: global -> LDS raw logits, track max(l).
    // IEEE div by T>0 is monotone, so max(l)/T == max(l/T) bitwise.
    float lmax = -__builtin_inff();
    for (int i = tid; i < NC4; i += BLOCK) {
        float4 v = row4[i];
        zb4[i] = v;
        lmax = fmaxf(lmax, fmaxf(fmaxf(v.x, v.y), fmaxf(v.z, v.w)));
    }
    lmax = waveMax(lmax);
    if (lane == 0) s_red[wave] = lmax;
    __syncthreads();
    if (tid == 0) {
        float mm = s_red[0];
        #pragma unroll
        for (int w = 1; w < NWAVE; ++w) mm = fmaxf(mm, s_red[w]);
        s_bcast = mm / T;   // bitwise == max over z = l/T
    }
    __syncthreads();
    const float m = s_bcast;

    // ---- Pass 2: e = exp(l/T - m), overwrite LDS, accumulate sum.
    // z = l/T exact IEEE div (matches ref's elementwise divide).
    float lsum = 0.0f;
    for (int i = tid; i < NC4; i += BLOCK) {
        float4 v = zb4[i];
        float4 e;
        e.x = expf(v.x / T - m);
        e.y = expf(v.y / T - m);
        e.z = expf(v.z / T - m);
        e.w = expf(v.w / T - m);
        zb4[i] = e;
        lsum += e.x + e.y + e.z + e.w;
    }
    lsum = waveSum(lsum);
    if (lane == 0) s_red[wave] = lsum;
    __syncthreads();
    if (tid == 0) {
        float s = 0.0f;
        #pragma unroll
        for (int w = 0; w < NWAVE; ++w) s += s_red[w];
        s_bcast = s;
    }
    __syncthreads();
    const float S = s_bcast;

    // ---- Pass 3: p = e/S, idx = searchsorted(mids, p, left), out = y[idx].
    // Fast path: e < ecut guarantees fl(e/S) < mids[0] -> idx 0.
    // ecut = mids[0]*S scaled down by ~1e-6 (>> the <=1ulp error of the div).
    const float mids0 = s_mids[0];
    const float y0    = s_y[0];
    const float ecut  = mids0 * S * 0.999999f;

    for (int i = tid; i < NC4; i += BLOCK) {
        float4 e = zb4[i];
        vfloat4 o;
        if (e.x < ecut && e.y < ecut && e.z < ecut && e.w < ecut) {
            o = (vfloat4){y0, y0, y0, y0};
        } else {
            float pe[4] = {e.x, e.y, e.z, e.w};
            float po[4];
            #pragma unroll
            for (int k = 0; k < 4; ++k) {
                if (pe[k] < ecut) { po[k] = y0; continue; }
                float p = pe[k] / S;            // exact, matches ref
                int ii = 0;
                while (ii < NMID && s_mids[ii] < p) ++ii;
                po[k] = s_y[ii];
            }
            o = (vfloat4){po[0], po[1], po[2], po[3]};
        }
        __builtin_nontemporal_store(o, &out4[i]);  // don't evict L3-warm logits
    }
}

extern "C" void kernel_launch(void* const* d_in, const int* in_sizes, int n_in,
                              void* d_out, int out_size, void* d_ws, size_t ws_size,
                              hipStream_t stream) {
    const float* logits = (const float*)d_in[0];
    const float* logT   = (const float*)d_in[1];
    const float* iso_x  = (const float*)d_in[2];
    const float* iso_y  = (const float*)d_in[3];
    float* out = (float*)d_out;
    calib_kernel<<<NROWS, BLOCK, 0, stream>>>(logits, logT, iso_x, iso_y, out);
}